// Round 10
// baseline (54.880 us; speedup 1.0000x reference)
//
#include <hip/hip_runtime.h>

#define IMG   224
#define IMG2  (IMG*IMG)
#define NN    27          // patches per dim
#define KK    256         // pixels per patch
#define EE    128
#define NSTRIP 28         // output 8-row strips
#define SCOLS 232         // strip row stride in elems
#define RSTR  132         // rec row stride in elems

typedef float f32x4 __attribute__((ext_vector_type(4)));
typedef short s16x8 __attribute__((ext_vector_type(8)));

__device__ __forceinline__ unsigned short f2bf(float f) {
    unsigned int u = __float_as_uint(f);
    u = (u + 0x7fffu + ((u >> 16) & 1u)) >> 16;   // RNE (inputs finite)
    return (unsigned short)u;
}
__device__ __forceinline__ float bf2f(unsigned short u) {
    return __uint_as_float((unsigned int)u << 16);
}
// register-only packed cvt (RNE). Single-instruction asm statements: inputs are
// read before dst is written, so no early-clobber hazard.
__device__ __forceinline__ uint2 pack4(f32x4 r) {
    uint2 u;
    asm("v_cvt_pk_bf16_f32 %0, %1, %2" : "=v"(u.x) : "v"(r.x), "v"(r.y));
    asm("v_cvt_pk_bf16_f32 %0, %1, %2" : "=v"(u.y) : "v"(r.z), "v"(r.w));
    return u;
}

// M[c][k][j] = sum_e W_dec[c][k][e]*W_enc[c][e][j], packed in MFMA A-frag order:
// APK[c][kf(16)][jb(8)][lane(64)][i(8)] = bf16(M[kf*16+(lane&15)][jb*32+8*(lane>>4)+i])
// Also v[c][k] = b_dec[c][k] + sum_e W_dec[c][k][e]*b_enc[c][e].
__global__ void pack_M(const float* __restrict__ W_enc, const float* __restrict__ W_dec,
                       const float* __restrict__ b_enc, const float* __restrict__ b_dec,
                       unsigned short* __restrict__ APK, float* __restrict__ v) {
    int k = blockIdx.x, c = blockIdx.y, j = threadIdx.x;
    const float* wd = W_dec + ((size_t)c*KK + k)*EE;
    const float* we = W_enc + (size_t)c*EE*KK + j;
    float acc = 0.f;
    #pragma unroll 8
    for (int e = 0; e < EE; ++e) acc = fmaf(wd[e], we[(size_t)e*KK], acc);
    int kf = k >> 4, kr = k & 15, jb = j >> 5, g = (j >> 3) & 3, i = j & 7;
    APK[(size_t)c*65536 + (((kf*8 + jb)*64) + g*16 + kr)*8 + i] = f2bf(acc);

    __shared__ float pv[128];
    if (j < EE) pv[j] = wd[j] * b_enc[c*EE + j];
    __syncthreads();
    for (int off = 64; off > 0; off >>= 1) {
        if (j < off) pv[j] += pv[j + off];
        __syncthreads();
    }
    if (j == 0) v[c*KK + k] = pv[0] + b_dec[c*KK + k];
}

// Block = (strip s, channel c, image pair bp). Each A-fragment feeds 2 images (16 MFMA/jb).
__global__ __launch_bounds__(256, 4)
void patch_ae_mfma(const float* __restrict__ x, const unsigned short* __restrict__ APK,
                   const float* __restrict__ v, float* __restrict__ out) {
    // bijective XCD swizzle: 2688 blocks = 8 XCDs x 336
    const int hid = blockIdx.x + NSTRIP*(blockIdx.y + 3*blockIdx.z);
    const int lid = (hid & 7)*336 + (hid >> 3);
    const int s  = lid % NSTRIP;
    const int t2 = lid / NSTRIP;
    const int c  = t2 % 3;
    const int b0 = (t2 / 3) * 2;          // images b0, b0+1

    const int tid  = threadIdx.x;
    const int lane = tid & 63, wave = tid >> 6;

    __shared__ __align__(16) unsigned short strip[2][24*SCOLS]; // 22272 B
    __shared__ __align__(16) unsigned short rec[2][28][RSTR];   // 14784 B (reused img0 then img1)
    __shared__ __align__(16) float vsh[256];                    // 1024 B

    vsh[tid] = v[c*256 + tid];

    // wave constants
    const int prow    = wave >> 1;       // 0: ny=s (strip row 8), 1: ny=s-1 (strip row 0)
    const int kq      = wave & 1;
    const int rowbase = prow ? 0 : 8;
    const int kfbase  = prow*8 + kq*4;
    const int g = lane >> 4, lr = lane & 15;
    const s16x8* APKc = (const s16x8*)(APK + (size_t)c*65536);

    // depth-2 A prefetch: jb=0 -> a0, jb=1 -> a1, issued before staging
    s16x8 a0[4], a1[4];
    #pragma unroll
    for (int f = 0; f < 4; ++f) a0[f] = APKc[((kfbase + f)*8 + 0)*64 + lane];
    #pragma unroll
    for (int f = 0; f < 4; ++f) a1[f] = APKc[((kfbase + f)*8 + 1)*64 + lane];

    // ---- stage input strips (both images), rows [8s-8, 8s+16), f32 -> bf16 ----
    if (tid < 224) {
        const int ybase = 8*s - 8;
        const int r0 = tid / 56;
        const int c4 = tid - r0*56;
        #pragma unroll
        for (int img = 0; img < 2; ++img) {
            const float* xb = x + (size_t)((b0 + img)*3 + c)*IMG2;
            #pragma unroll
            for (int it = 0; it < 6; ++it) {
                int r  = r0 + it*4;
                int yr = ybase + r;
                float4 xv = make_float4(0.f, 0.f, 0.f, 0.f);
                if ((unsigned)yr < IMG)
                    xv = ((const float4*)(xb + (size_t)yr*IMG))[c4];
                f32x4 xr = {xv.x, xv.y, xv.z, xv.w};
                *((uint2*)&strip[img][r*SCOLS + c4*4]) = pack4(xr);
            }
        }
    }
    __syncthreads();

    // ---- MFMA: per jb, 4 shared A-frags x 4 B-frags (2 img x 2 pf) = 16 MFMA ----
    f32x4 acc[4][2][2];   // [f][img][pf]
    #pragma unroll
    for (int f = 0; f < 4; ++f)
        #pragma unroll
        for (int im = 0; im < 2; ++im)
            #pragma unroll
            for (int pf = 0; pf < 2; ++pf)
                acc[f][im][pf] = (f32x4){0.f, 0.f, 0.f, 0.f};

    // pf1 column: patches 16+lr; lanes lr>=11 (p>=27 unused) clamped in-bounds
    const int c1 = (lr <= 10) ? (128 + 8*lr) : 208;

    #pragma unroll
    for (int jb = 0; jb < 8; ++jb) {
        const int jy  = 2*jb + (g >> 1);
        const int jx0 = (g & 1)*8;
        const unsigned short* s0 = &strip[0][(rowbase + jy)*SCOLS + jx0];
        const unsigned short* s1 = &strip[1][(rowbase + jy)*SCOLS + jx0];
        s16x8 b00 = *((const s16x8*)&s0[8*lr]);
        s16x8 b01 = *((const s16x8*)&s0[c1]);
        s16x8 b10 = *((const s16x8*)&s1[8*lr]);
        s16x8 b11 = *((const s16x8*)&s1[c1]);
        if ((jb & 1) == 0) {
            __builtin_amdgcn_s_setprio(1);
            #pragma unroll
            for (int f = 0; f < 4; ++f) {
                acc[f][0][0] = __builtin_amdgcn_mfma_f32_16x16x32_bf16(a0[f], b00, acc[f][0][0], 0, 0, 0);
                acc[f][0][1] = __builtin_amdgcn_mfma_f32_16x16x32_bf16(a0[f], b01, acc[f][0][1], 0, 0, 0);
                acc[f][1][0] = __builtin_amdgcn_mfma_f32_16x16x32_bf16(a0[f], b10, acc[f][1][0], 0, 0, 0);
                acc[f][1][1] = __builtin_amdgcn_mfma_f32_16x16x32_bf16(a0[f], b11, acc[f][1][1], 0, 0, 0);
            }
            __builtin_amdgcn_s_setprio(0);
            if (jb < 6) {
                #pragma unroll
                for (int f = 0; f < 4; ++f)
                    a0[f] = APKc[((kfbase + f)*8 + (jb+2))*64 + lane];
            }
        } else {
            __builtin_amdgcn_s_setprio(1);
            #pragma unroll
            for (int f = 0; f < 4; ++f) {
                acc[f][0][0] = __builtin_amdgcn_mfma_f32_16x16x32_bf16(a1[f], b00, acc[f][0][0], 0, 0, 0);
                acc[f][0][1] = __builtin_amdgcn_mfma_f32_16x16x32_bf16(a1[f], b01, acc[f][0][1], 0, 0, 0);
                acc[f][1][0] = __builtin_amdgcn_mfma_f32_16x16x32_bf16(a1[f], b10, acc[f][1][0], 0, 0, 0);
                acc[f][1][1] = __builtin_amdgcn_mfma_f32_16x16x32_bf16(a1[f], b11, acc[f][1][1], 0, 0, 0);
            }
            __builtin_amdgcn_s_setprio(0);
            if (jb < 6) {
                #pragma unroll
                for (int f = 0; f < 4; ++f)
                    a1[f] = APKc[((kfbase + f)*8 + (jb+2))*64 + lane];
            }
        }
    }

    // ---- per image: rec store -> epilogue (rec buffer reused) ----
    // epilogue constants (wave-invariant per thread)
    const int xc  = tid;                      // valid when tid<224
    const int p1  = xc >> 3;
    const int v1  = (p1 <= NN-1);
    const int v0e = (p1 > 0);
    const int p0v = v0e ? p1 - 1 : 0;
    const int dx1 = xc & 7, dx0 = dx1 + 8;
    const int h0  = (s < NSTRIP-1);
    const int h1  = (s > 0);
    const int shift = (v0e & v1) + (h0 & h1);
    const float inv = __int_as_float(0x3f800000 - (shift << 23)); // exact 1/2^shift

    #pragma unroll
    for (int img = 0; img < 2; ++img) {
        __syncthreads();   // img0: after MFMA; img1: after epilogue(img0) reads
        // bias + bf16 store: rec[prow][p][klocal], k = prow*128 + klocal
        #pragma unroll
        for (int f = 0; f < 4; ++f) {
            int klocal = kq*64 + f*16 + g*4;
            f32x4 bias = *((const f32x4*)&vsh[prow*128 + klocal]);
            #pragma unroll
            for (int pf = 0; pf < 2; ++pf) {
                f32x4 r = acc[f][img][pf] + bias;
                int p = min(pf*16 + lr, 27);      // p>=27 -> dump row (never read)
                *((uint2*)&rec[prow][p][klocal]) = pack4(r);
            }
        }
        __syncthreads();
        if (tid < 224) {
            float* orow = out + (size_t)((b0 + img)*3 + c)*IMG2 + (size_t)(8*s)*IMG + xc;
            #pragma unroll
            for (int ry = 0; ry < 8; ++ry) {
                int kl1 = ry*16 + dx1, kl0 = ry*16 + dx0;
                float sum = 0.f;
                if (v1) {
                    if (h0) sum += bf2f(rec[0][p1][kl1]);
                    if (h1) sum += bf2f(rec[1][p1][kl1]);
                }
                if (v0e) {
                    if (h0) sum += bf2f(rec[0][p0v][kl0]);
                    if (h1) sum += bf2f(rec[1][p0v][kl0]);
                }
                orow[(size_t)ry*IMG] = sum * inv;
            }
        }
    }
}

extern "C" void kernel_launch(void* const* d_in, const int* in_sizes, int n_in,
                              void* d_out, int out_size, void* d_ws, size_t ws_size,
                              hipStream_t stream) {
    (void)in_sizes; (void)n_in; (void)out_size; (void)ws_size;
    const float* x     = (const float*)d_in[0];
    const float* W_enc = (const float*)d_in[1];
    const float* b_enc = (const float*)d_in[2];
    const float* W_dec = (const float*)d_in[3];
    const float* b_dec = (const float*)d_in[4];
    float* out = (float*)d_out;

    float*          v   = (float*)d_ws;                          // 768 f32
    unsigned short* APK = (unsigned short*)((char*)d_ws + 4096); // 3 x 65536 bf16 = 384 KB

    pack_M<<<dim3(KK, 3), 256, 0, stream>>>(W_enc, W_dec, b_enc, b_dec, APK, v);
    patch_ae_mfma<<<dim3(NSTRIP, 3, 32), 256, 0, stream>>>(x, APK, v, out);
}

// Round 11
// 48.579 us; speedup vs baseline: 1.1297x; 1.1297x over previous
//
#include <hip/hip_runtime.h>

#define IMG   224
#define IMG2  (IMG*IMG)
#define NN    27          // patches per dim
#define KK    256         // pixels per patch
#define EE    128
#define NSTRIP 28         // output 8-row strips
#define SCOLS 232         // strip row stride in elems (464 B = 29*16, b128-aligned)
#define RSTR  136         // rec row stride in elems (272 B = 17*16, b128-aligned)

typedef float f32x4 __attribute__((ext_vector_type(4)));
typedef short s16x8 __attribute__((ext_vector_type(8)));

__device__ __forceinline__ unsigned short f2bf(float f) {
    unsigned int u = __float_as_uint(f);
    u = (u + 0x7fffu + ((u >> 16) & 1u)) >> 16;   // RNE (inputs finite)
    return (unsigned short)u;
}
__device__ __forceinline__ float bf2f(unsigned short u) {
    return __uint_as_float((unsigned int)u << 16);
}
// register-only packed cvt (RNE); single-instruction asm, no early-clobber hazard
__device__ __forceinline__ uint2 pack4(f32x4 r) {
    uint2 u;
    asm("v_cvt_pk_bf16_f32 %0, %1, %2" : "=v"(u.x) : "v"(r.x), "v"(r.y));
    asm("v_cvt_pk_bf16_f32 %0, %1, %2" : "=v"(u.y) : "v"(r.z), "v"(r.w));
    return u;
}

// M[c][k][j] = sum_e W_dec[c][k][e]*W_enc[c][e][j], packed in MFMA A-frag order:
// APK[c][kf(16)][jb(8)][lane(64)][i(8)] = bf16(M[kf*16+(lane&15)][jb*32+8*(lane>>4)+i])
// Also v[c][k] = b_dec[c][k] + sum_e W_dec[c][k][e]*b_enc[c][e].
__global__ void pack_M(const float* __restrict__ W_enc, const float* __restrict__ W_dec,
                       const float* __restrict__ b_enc, const float* __restrict__ b_dec,
                       unsigned short* __restrict__ APK, float* __restrict__ v) {
    int k = blockIdx.x, c = blockIdx.y, j = threadIdx.x;
    const float* wd = W_dec + ((size_t)c*KK + k)*EE;
    const float* we = W_enc + (size_t)c*EE*KK + j;
    float acc = 0.f;
    #pragma unroll 8
    for (int e = 0; e < EE; ++e) acc = fmaf(wd[e], we[(size_t)e*KK], acc);
    int kf = k >> 4, kr = k & 15, jb = j >> 5, g = (j >> 3) & 3, i = j & 7;
    APK[(size_t)c*65536 + (((kf*8 + jb)*64) + g*16 + kr)*8 + i] = f2bf(acc);

    __shared__ float pv[128];
    if (j < EE) pv[j] = wd[j] * b_enc[c*EE + j];
    __syncthreads();
    for (int off = 64; off > 0; off >>= 1) {
        if (j < off) pv[j] += pv[j + off];
        __syncthreads();
    }
    if (j == 0) v[c*KK + k] = pv[0] + b_dec[c*KK + k];
}

__global__ __launch_bounds__(256, 5)
void patch_ae_mfma(const float* __restrict__ x, const unsigned short* __restrict__ APK,
                   const float* __restrict__ v, float* __restrict__ out) {
    // bijective XCD swizzle: 5376 blocks = 8 XCDs x 672
    const int hid = blockIdx.x + NSTRIP*(blockIdx.y + 3*blockIdx.z);
    const int lid = (hid & 7)*672 + (hid >> 3);
    const int s  = lid % NSTRIP;
    const int t2 = lid / NSTRIP;
    const int c  = t2 % 3;
    const int b  = t2 / 3;

    const int tid  = threadIdx.x;
    const int lane = tid & 63, wave = tid >> 6;

    __shared__ __align__(16) unsigned short strip[24*SCOLS];   // 11136 B
    // rec slots: 0 = zero row, 1..27 = patches 0..26, 28 = zero row, 29 = dump (p>=27)
    __shared__ __align__(16) unsigned short rec[2][30][RSTR];  // 16320 B
    __shared__ __align__(16) float vsh[256];                   // 1024 B

    vsh[tid] = v[c*256 + tid];
    if (tid < RSTR) {   // zero rows (slots 0 and 28, both prows)
        rec[0][0][tid] = 0; rec[0][28][tid] = 0;
        rec[1][0][tid] = 0; rec[1][28][tid] = 0;
    }

    // wave constants
    const int prow    = wave >> 1;       // 0: ny=s (strip row 8), 1: ny=s-1 (strip row 0)
    const int kq      = wave & 1;
    const int rowbase = prow ? 0 : 8;
    const int kfbase  = prow*8 + kq*4;
    const int g = lane >> 4, lr = lane & 15;
    const s16x8* APKc = (const s16x8*)(APK + (size_t)c*65536);

    // depth-2 A prefetch: jb=0 -> a0, jb=1 -> a1, issued before staging
    s16x8 a0[4], a1[4];
    #pragma unroll
    for (int f = 0; f < 4; ++f) a0[f] = APKc[((kfbase + f)*8 + 0)*64 + lane];
    #pragma unroll
    for (int f = 0; f < 4; ++f) a1[f] = APKc[((kfbase + f)*8 + 1)*64 + lane];

    // ---- stage input strip rows [8s-8, 8s+16), cols [0,224), f32 -> bf16 ----
    // chunk = 32B of f32 (8 px) -> one ds_write_b128; 28 chunks/row, 672 total
    {
        const float* xb = x + (size_t)(b*3 + c)*IMG2;
        const int ybase = 8*s - 8;
        #pragma unroll
        for (int it = 0; it < 3; ++it) {
            int ci = tid + it*256;
            if (ci < 672) {
                int r  = ci / 28;
                int cc = ci - r*28;
                int yr = ybase + r;
                float4 lo = make_float4(0.f,0.f,0.f,0.f), hi = lo;
                if ((unsigned)yr < IMG) {
                    const float4* src = (const float4*)(xb + (size_t)yr*IMG + cc*8);
                    lo = src[0]; hi = src[1];
                }
                uint2 u0 = pack4((f32x4){lo.x, lo.y, lo.z, lo.w});
                uint2 u1 = pack4((f32x4){hi.x, hi.y, hi.z, hi.w});
                *((uint4*)&strip[r*SCOLS + cc*8]) = make_uint4(u0.x, u0.y, u1.x, u1.y);
            }
        }
    }
    __syncthreads();

    // ---- MFMA with depth-2 alternating-buffer A pipeline ----
    {
        f32x4 acc[4][2];
        #pragma unroll
        for (int f = 0; f < 4; ++f)
            #pragma unroll
            for (int pf = 0; pf < 2; ++pf)
                acc[f][pf] = (f32x4){0.f, 0.f, 0.f, 0.f};

        // pf1 column: patches 16+lr; lanes lr>=11 (p>=27 unused) clamped in-bounds
        const int c1 = (lr <= 10) ? (128 + 8*lr) : 208;

        #pragma unroll
        for (int jb = 0; jb < 8; ++jb) {
            const int jy  = 2*jb + (g >> 1);
            const int jx0 = (g & 1)*8;
            const unsigned short* srow = &strip[(rowbase + jy)*SCOLS + jx0];
            s16x8 bf0 = *((const s16x8*)&srow[8*lr]);
            s16x8 bf1 = *((const s16x8*)&srow[c1]);
            if ((jb & 1) == 0) {
                __builtin_amdgcn_s_setprio(1);
                #pragma unroll
                for (int f = 0; f < 4; ++f) {
                    acc[f][0] = __builtin_amdgcn_mfma_f32_16x16x32_bf16(a0[f], bf0, acc[f][0], 0, 0, 0);
                    acc[f][1] = __builtin_amdgcn_mfma_f32_16x16x32_bf16(a0[f], bf1, acc[f][1], 0, 0, 0);
                }
                __builtin_amdgcn_s_setprio(0);
                if (jb < 6) {
                    #pragma unroll
                    for (int f = 0; f < 4; ++f)
                        a0[f] = APKc[((kfbase + f)*8 + (jb+2))*64 + lane];
                }
            } else {
                __builtin_amdgcn_s_setprio(1);
                #pragma unroll
                for (int f = 0; f < 4; ++f) {
                    acc[f][0] = __builtin_amdgcn_mfma_f32_16x16x32_bf16(a1[f], bf0, acc[f][0], 0, 0, 0);
                    acc[f][1] = __builtin_amdgcn_mfma_f32_16x16x32_bf16(a1[f], bf1, acc[f][1], 0, 0, 0);
                }
                __builtin_amdgcn_s_setprio(0);
                if (jb < 6) {
                    #pragma unroll
                    for (int f = 0; f < 4; ++f)
                        a1[f] = APKc[((kfbase + f)*8 + (jb+2))*64 + lane];
                }
            }
        }

        // bias + bf16 store: patch p -> slot p+1 (p>=27 -> dump slot 29)
        #pragma unroll
        for (int f = 0; f < 4; ++f) {
            int klocal = kq*64 + f*16 + g*4;
            f32x4 bias = *((const f32x4*)&vsh[prow*128 + klocal]);
            #pragma unroll
            for (int pf = 0; pf < 2; ++pf) {
                f32x4 r = acc[f][pf] + bias;
                int pidx = pf*16 + lr + 1;
                if (pidx >= 28) pidx = 29;        // keep slot 28 = zeros
                *((uint2*)&rec[prow][pidx][klocal]) = pack4(r);
            }
        }
    }
    __syncthreads();

    // ---- epilogue: thread = (row ry, 8-col group q); 4 b128 reads, 2 dwordx4 stores ----
    if (tid < 224) {
        const int q  = tid % 28;           // col group: out cols 8q..8q+7
        const int ry = tid / 28;           // 0..7
        const int v1 = (q < 27);           // right patch (p1=q) exists
        const int v0 = (q > 0);            // left patch (p0=q-1) exists
        const int h0 = (s < NSTRIP-1);
        const int h1 = (s > 0);
        const int shift = (v0 & v1) + (h0 & h1);
        const float inv = __int_as_float(0x3f800000 - (shift << 23)); // exact 1/2^shift
        const int ro = ry*16;

        float sum[8];
        #pragma unroll
        for (int d = 0; d < 8; ++d) sum[d] = 0.f;
        if (h0) {
            s16x8 rr = *((const s16x8*)&rec[0][q+1][ro]);     // right: patch q (slot q+1)
            s16x8 ll = *((const s16x8*)&rec[0][q][ro + 8]);   // left: patch q-1 (slot q)
            #pragma unroll
            for (int d = 0; d < 8; ++d)
                sum[d] += bf2f((unsigned short)rr[d]) + bf2f((unsigned short)ll[d]);
        }
        if (h1) {
            s16x8 rr = *((const s16x8*)&rec[1][q+1][ro]);
            s16x8 ll = *((const s16x8*)&rec[1][q][ro + 8]);
            #pragma unroll
            for (int d = 0; d < 8; ++d)
                sum[d] += bf2f((unsigned short)rr[d]) + bf2f((unsigned short)ll[d]);
        }
        float* orow = out + (size_t)(b*3 + c)*IMG2 + (size_t)(8*s + ry)*IMG + 8*q;
        f32x4 o0 = {sum[0]*inv, sum[1]*inv, sum[2]*inv, sum[3]*inv};
        f32x4 o1 = {sum[4]*inv, sum[5]*inv, sum[6]*inv, sum[7]*inv};
        *((f32x4*)orow)       = o0;
        *((f32x4*)(orow + 4)) = o1;
    }
}

extern "C" void kernel_launch(void* const* d_in, const int* in_sizes, int n_in,
                              void* d_out, int out_size, void* d_ws, size_t ws_size,
                              hipStream_t stream) {
    (void)in_sizes; (void)n_in; (void)out_size; (void)ws_size;
    const float* x     = (const float*)d_in[0];
    const float* W_enc = (const float*)d_in[1];
    const float* b_enc = (const float*)d_in[2];
    const float* W_dec = (const float*)d_in[3];
    const float* b_dec = (const float*)d_in[4];
    float* out = (float*)d_out;

    float*          v   = (float*)d_ws;                          // 768 f32
    unsigned short* APK = (unsigned short*)((char*)d_ws + 4096); // 3 x 65536 bf16 = 384 KB

    pack_M<<<dim3(KK, 3), 256, 0, stream>>>(W_enc, W_dec, b_enc, b_dec, APK, v);
    patch_ae_mfma<<<dim3(NSTRIP, 3, 64), 256, 0, stream>>>(x, APK, v, out);
}